// Round 14
// baseline (353.612 us; speedup 1.0000x reference)
//
#include <hip/hip_runtime.h>
#include <hip/hip_bf16.h>
#include <cstddef>

#define D_    256
#define NH_   8
#define HD_   32
#define LQ_   300
#define BS_   16
#define LENV_ 13294
#define DFF_  1024
#define NROWS (BS_*LQ_)          // 4800
#define VROWS (BS_*LENV_)        // 212704 (= 16 * 13294 exactly)

typedef __attribute__((ext_vector_type(8))) short short8;
typedef __attribute__((ext_vector_type(4))) float f32x4;
typedef unsigned int u32;

__device__ __forceinline__ short f2bf(float x) {
    unsigned u = __float_as_uint(x);
    u += 0x7fff + ((u >> 16) & 1);     // RNE (inputs are finite)
    return (short)(u >> 16);
}
__device__ __forceinline__ unsigned pack_bf2(float lo, float hi) {
    return (unsigned)(unsigned short)f2bf(lo) | ((unsigned)(unsigned short)f2bf(hi) << 16);
}
__device__ __forceinline__ float bf2f(short s) {
    return __uint_as_float((unsigned)(unsigned short)s << 16);
}

// ---------------------------------------------------------------------------
// One-shot prep: weight transposes (f32 [K][N] -> bf16 [N][K]) + fused biases.
// ---------------------------------------------------------------------------
__global__ __launch_bounds__(256) void prep_all(
    const float* __restrict__ Wq, const float* __restrict__ Wk,
    const float* __restrict__ Wv, const float* __restrict__ Wo,
    const float* __restrict__ Wvp, const float* __restrict__ Wso,
    const float* __restrict__ Waw, const float* __restrict__ Wop,
    const float* __restrict__ W1, const float* __restrict__ W2,
    const float* __restrict__ bqp, const float* __restrict__ bkp,
    const float* __restrict__ bvp, const float* __restrict__ bsop,
    const float* __restrict__ bawp,
    short* __restrict__ Wqkvt, short* __restrict__ Wot,
    short* __restrict__ Wvpt, short* __restrict__ Wsoawt,
    short* __restrict__ Wopt, short* __restrict__ W1t,
    short* __restrict__ W2t, float* __restrict__ bqkv,
    float* __restrict__ bsoaw)
{
    const int blk = blockIdx.x, tid = threadIdx.x;
    if (blk < 1792) {                      // 7 square 256x256 transposes
        const int seg = blk >> 8;
        const int e = ((blk & 255) << 8) | tid;
        const int n = e >> 8, k = e & 255;
        const float* src; short* dst;
        switch (seg) {
            case 0: src = Wq;  dst = Wqkvt;          break;
            case 1: src = Wk;  dst = Wqkvt + 65536;  break;
            case 2: src = Wv;  dst = Wqkvt + 131072; break;
            case 3: src = Wo;  dst = Wot;            break;
            case 4: src = Wvp; dst = Wvpt;           break;
            case 5: src = Wso; dst = Wsoawt;         break;
            default: src = Wop; dst = Wopt;          break;
        }
        dst[e] = f2bf(src[(size_t)k * 256 + n]);
    } else if (blk < 1920) {               // Waw [256][128] -> rows 256..383
        const int e = ((blk - 1792) << 8) | tid;
        const int n = e >> 8, k = e & 255;
        Wsoawt[65536 + e] = f2bf(Waw[(size_t)k * 128 + n]);
    } else if (blk < 2048) {               // zero-pad rows 384..511
        const int e = ((blk - 1920) << 8) | tid;
        Wsoawt[98304 + e] = 0;
    } else if (blk < 3072) {               // W1 [256][1024] -> [1024][256]
        const int e = ((blk - 2048) << 8) | tid;
        const int n = e >> 8, k = e & 255;
        W1t[e] = f2bf(W1[(size_t)k * 1024 + n]);
    } else if (blk < 4096) {               // W2 [1024][256] -> [256][1024]
        const int e = ((blk - 3072) << 8) | tid;
        const int n = e / 1024, k = e % 1024;
        W2t[e] = f2bf(W2[(size_t)k * 256 + n]);
    } else {                               // biases
        const int e = ((blk - 4096) << 8) | tid;
        if (e < 768)
            bqkv[e] = (e < 256) ? bqp[e] : (e < 512) ? bkp[e - 256] : bvp[e - 512];
        else if (e < 1280) {
            const int f = e - 768;
            bsoaw[f] = (f < 256) ? bsop[f] : (f < 384) ? bawp[f - 256] : 0.f;
        }
    }
}

// ---------------------------------------------------------------------------
// Pipelined bf16 MFMA GEMM, tile BM x 256 (BM = 64 or 32).
// FUSE_LN=1 (requires N=256, STACKED=0, M%BM==0): out = LN(acc+bias+resid)*g+b
// ---------------------------------------------------------------------------
template<int ACT, int OUT_BF16, int STACKED, int FUSE_LN, int BM>
__global__ __launch_bounds__(256) void mfma_gemm(
    const float* __restrict__ A, const short* __restrict__ Wt,
    const float* __restrict__ bias, void* __restrict__ Cout,
    int M, int N, int K,
    const float* __restrict__ resid, const float* __restrict__ lng,
    const float* __restrict__ lnb)
{
    constexpr int MR = BM / 16;
    __shared__ short Alds[2][BM * 40];
    __shared__ short Blds[2][256 * 40];
    const int tid  = threadIdx.x;
    const int lane = tid & 63;
    const int wn   = tid >> 6;
    const int m0   = blockIdx.x * BM;
    const int nb   = blockIdx.y;
    const int srow = tid >> 2;              // 0..63
    const int schk = tid & 3;

    const bool sA   = (BM == 64) || (srow < BM);
    const int  arow = m0 + (sA ? srow : 0);
    const bool aok  = sA && (arow < M);
    const float* aptr = &A[(size_t)(aok ? arow : 0) * K + schk * 8];
    const short* bptr = &Wt[(size_t)(nb * 256 + srow) * K + schk * 8];

    f32x4 acc[MR][4] = {};
    float4 ra0, ra1;
    short8 rb0, rb1, rb2, rb3;

    ra0 = make_float4(0.f, 0.f, 0.f, 0.f); ra1 = ra0;
    if (aok) { ra0 = *(const float4*)(aptr); ra1 = *(const float4*)(aptr + 4); }
    rb0 = *(const short8*)(bptr);
    rb1 = *(const short8*)(bptr + (size_t)64 * K);
    rb2 = *(const short8*)(bptr + (size_t)128 * K);
    rb3 = *(const short8*)(bptr + (size_t)192 * K);
    {
        if (sA) {
            short8 s;
            s[0] = f2bf(ra0.x); s[1] = f2bf(ra0.y); s[2] = f2bf(ra0.z); s[3] = f2bf(ra0.w);
            s[4] = f2bf(ra1.x); s[5] = f2bf(ra1.y); s[6] = f2bf(ra1.z); s[7] = f2bf(ra1.w);
            *(short8*)&Alds[0][srow * 40 + schk * 8] = s;
        }
        *(short8*)&Blds[0][(srow +   0) * 40 + schk * 8] = rb0;
        *(short8*)&Blds[0][(srow +  64) * 40 + schk * 8] = rb1;
        *(short8*)&Blds[0][(srow + 128) * 40 + schk * 8] = rb2;
        *(short8*)&Blds[0][(srow + 192) * 40 + schk * 8] = rb3;
    }
    __syncthreads();

    const int lg = lane >> 4;
    const int lr = lane & 15;
    int buf = 0;

    for (int k0 = 32; k0 < K; k0 += 32) {
        ra0 = make_float4(0.f, 0.f, 0.f, 0.f); ra1 = ra0;
        if (aok) { ra0 = *(const float4*)(aptr + k0); ra1 = *(const float4*)(aptr + k0 + 4); }
        rb0 = *(const short8*)(bptr + k0);
        rb1 = *(const short8*)(bptr + k0 + (size_t)64 * K);
        rb2 = *(const short8*)(bptr + k0 + (size_t)128 * K);
        rb3 = *(const short8*)(bptr + k0 + (size_t)192 * K);

        {
            short8 a[MR], b[4];
            #pragma unroll
            for (int mr = 0; mr < MR; ++mr)
                a[mr] = *(const short8*)&Alds[buf][(mr * 16 + lr) * 40 + lg * 8];
            #pragma unroll
            for (int nr = 0; nr < 4; ++nr)
                b[nr] = *(const short8*)&Blds[buf][(wn * 64 + nr * 16 + lr) * 40 + lg * 8];
            #pragma unroll
            for (int mr = 0; mr < MR; ++mr)
                #pragma unroll
                for (int nr = 0; nr < 4; ++nr)
                    acc[mr][nr] = __builtin_amdgcn_mfma_f32_16x16x32_bf16(
                        a[mr], b[nr], acc[mr][nr], 0, 0, 0);
        }

        {
            const int ob = buf ^ 1;
            if (sA) {
                short8 s;
                s[0] = f2bf(ra0.x); s[1] = f2bf(ra0.y); s[2] = f2bf(ra0.z); s[3] = f2bf(ra0.w);
                s[4] = f2bf(ra1.x); s[5] = f2bf(ra1.y); s[6] = f2bf(ra1.z); s[7] = f2bf(ra1.w);
                *(short8*)&Alds[ob][srow * 40 + schk * 8] = s;
            }
            *(short8*)&Blds[ob][(srow +   0) * 40 + schk * 8] = rb0;
            *(short8*)&Blds[ob][(srow +  64) * 40 + schk * 8] = rb1;
            *(short8*)&Blds[ob][(srow + 128) * 40 + schk * 8] = rb2;
            *(short8*)&Blds[ob][(srow + 192) * 40 + schk * 8] = rb3;
        }
        __syncthreads();
        buf ^= 1;
    }

    {
        short8 a[MR], b[4];
        #pragma unroll
        for (int mr = 0; mr < MR; ++mr)
            a[mr] = *(const short8*)&Alds[buf][(mr * 16 + lr) * 40 + lg * 8];
        #pragma unroll
        for (int nr = 0; nr < 4; ++nr)
            b[nr] = *(const short8*)&Blds[buf][(wn * 64 + nr * 16 + lr) * 40 + lg * 8];
        #pragma unroll
        for (int mr = 0; mr < MR; ++mr)
            #pragma unroll
            for (int nr = 0; nr < 4; ++nr)
                acc[mr][nr] = __builtin_amdgcn_mfma_f32_16x16x32_bf16(
                    a[mr], b[nr], acc[mr][nr], 0, 0, 0);
    }

    if (FUSE_LN) {
        __shared__ float RedS[4][BM];
        __shared__ float RedS2[4][BM];
        float psum[MR][4] = {};
        float psq[MR][4]  = {};
        #pragma unroll
        for (int mr = 0; mr < MR; ++mr)
            #pragma unroll
            for (int r4 = 0; r4 < 4; ++r4) {
                const int row = m0 + mr * 16 + lg * 4 + r4;
                #pragma unroll
                for (int nr = 0; nr < 4; ++nr) {
                    const int col = wn * 64 + nr * 16 + lr;
                    float x = acc[mr][nr][r4] + bias[col]
                            + resid[(size_t)row * 256 + col];
                    acc[mr][nr][r4] = x;
                    psum[mr][r4] += x;
                    psq[mr][r4]  += x * x;
                }
            }
        #pragma unroll
        for (int o = 1; o < 16; o <<= 1)
            #pragma unroll
            for (int mr = 0; mr < MR; ++mr)
                #pragma unroll
                for (int r4 = 0; r4 < 4; ++r4) {
                    psum[mr][r4] += __shfl_xor(psum[mr][r4], o);
                    psq[mr][r4]  += __shfl_xor(psq[mr][r4], o);
                }
        if (lr == 0) {
            #pragma unroll
            for (int mr = 0; mr < MR; ++mr)
                #pragma unroll
                for (int r4 = 0; r4 < 4; ++r4) {
                    const int lrow = mr * 16 + lg * 4 + r4;
                    RedS[wn][lrow]  = psum[mr][r4];
                    RedS2[wn][lrow] = psq[mr][r4];
                }
        }
        __syncthreads();
        float* outp = (float*)Cout;
        #pragma unroll
        for (int mr = 0; mr < MR; ++mr)
            #pragma unroll
            for (int r4 = 0; r4 < 4; ++r4) {
                const int lrow = mr * 16 + lg * 4 + r4;
                const int row  = m0 + lrow;
                const float s  = RedS[0][lrow] + RedS[1][lrow] + RedS[2][lrow] + RedS[3][lrow];
                const float s2 = RedS2[0][lrow] + RedS2[1][lrow] + RedS2[2][lrow] + RedS2[3][lrow];
                const float mean = s * (1.f / 256.f);
                const float var  = s2 * (1.f / 256.f) - mean * mean;
                const float inv  = rsqrtf(var + 1e-5f);
                #pragma unroll
                for (int nr = 0; nr < 4; ++nr) {
                    const int col = wn * 64 + nr * 16 + lr;
                    outp[(size_t)row * 256 + col] =
                        (acc[mr][nr][r4] - mean) * inv * lng[col] + lnb[col];
                }
            }
        return;
    }

    if (STACKED) {
        float* Cb = (float*)Cout + (size_t)nb * M * 256;
        const float* bb = bias + nb * 256;
        #pragma unroll
        for (int mr = 0; mr < MR; ++mr)
            #pragma unroll
            for (int r = 0; r < 4; ++r) {
                const int row = m0 + mr * 16 + lg * 4 + r;
                if (row >= M) continue;
                #pragma unroll
                for (int nr = 0; nr < 4; ++nr) {
                    const int col = wn * 64 + nr * 16 + lr;
                    Cb[(size_t)row * 256 + col] = acc[mr][nr][r] + bb[col];
                }
            }
    } else {
        #pragma unroll
        for (int mr = 0; mr < MR; ++mr)
            #pragma unroll
            for (int r = 0; r < 4; ++r) {
                const int row = m0 + mr * 16 + lg * 4 + r;
                if (row >= M) continue;
                #pragma unroll
                for (int nr = 0; nr < 4; ++nr) {
                    const int col = nb * 256 + wn * 64 + nr * 16 + lr;
                    float v = acc[mr][nr][r] + bias[col];
                    if (ACT) v = fmaxf(v, 0.f);
                    if (OUT_BF16) ((short*)Cout)[(size_t)row * N + col] = f2bf(v);
                    else          ((float*)Cout)[(size_t)row * N + col] = v;
                }
            }
    }
}

// ---------------------------------------------------------------------------
// Value-projection (K=N=256) — counted-vmcnt async streamer, 16-row tiles,
// 40 KB LDS -> 4 blocks/CU (1024 blocks). Same skeleton as R11, scaled:
// 4 loads/wave per stage, 2 stores/thread copy-out, vmcnt(6)/(4)/(2).
// ---------------------------------------------------------------------------
__global__ __launch_bounds__(256, 4) void vp_gemm(
    const float* __restrict__ A, const short* __restrict__ Wt,
    const float* __restrict__ bias, short* __restrict__ C)
{
    __shared__ float Alds[2][16 * 256];   // 2 x 16 KB
    __shared__ short Cst[16 * 256];       // 8 KB
    const int tid  = threadIdx.x;
    const int lane = tid & 63;
    const int w    = tid >> 6;
    const int lr   = lane & 15;
    const int lg   = lane >> 4;

    short8 bf[4][8];
    #pragma unroll
    for (int nr = 0; nr < 4; ++nr) {
        const short* wp = &Wt[(size_t)(w * 64 + nr * 16 + lr) * 256 + lg * 8];
        #pragma unroll
        for (int kc = 0; kc < 8; ++kc)
            bf[nr][kc] = *(const short8*)(wp + kc * 32);
    }
    float bs[4];
    #pragma unroll
    for (int nr = 0; nr < 4; ++nr) bs[nr] = bias[w * 64 + nr * 16 + lr];

    const int NT = VROWS / 16;            // 13294 exact
    const int NB = 1024;

    #define VP_STAGE(BUFI, TILE)                                               \
        {                                                                      \
            _Pragma("unroll")                                                  \
            for (int j = 0; j < 4; ++j) {                                      \
                const int r = w * 4 + j;                                       \
                const int grow = (TILE) * 16 + r;                              \
                const int c16 = ((((lane >> 1) ^ (r & 7)) << 1) | (lane & 1)); \
                const float* src = A + (size_t)grow * 256 + c16 * 4;           \
                __builtin_amdgcn_global_load_lds(                              \
                    (const __attribute__((address_space(1))) u32*)src,         \
                    (__attribute__((address_space(3))) u32*)&Alds[BUFI][r*256],\
                    16, 0, 0);                                                 \
            }                                                                  \
        }

    int t  = blockIdx.x;
    int t2 = t + NB;
    bool has2 = (t2 < NT);
    int buf = 0;

    VP_STAGE(0, t);
    if (has2) VP_STAGE(1, t2);
    if (has2) { asm volatile("s_waitcnt vmcnt(4)" ::: "memory"); }
    else      { asm volatile("s_waitcnt vmcnt(0)" ::: "memory"); }
    __builtin_amdgcn_sched_barrier(0);
    __builtin_amdgcn_s_barrier();

    while (true) {
        f32x4 acc[4] = {};
        #pragma unroll
        for (int kc = 0; kc < 8; ++kc) {
            short8 a;
            {
                const int row = lr;
                const int c32 = (kc * 4 + lg) ^ (row & 7);
                const float* p = &Alds[buf][row * 256 + c32 * 8];
                float4 x = *(const float4*)(p);
                float4 y = *(const float4*)(p + 4);
                short8 s;
                s[0] = f2bf(x.x); s[1] = f2bf(x.y); s[2] = f2bf(x.z); s[3] = f2bf(x.w);
                s[4] = f2bf(y.x); s[5] = f2bf(y.y); s[6] = f2bf(y.z); s[7] = f2bf(y.w);
                a = s;
            }
            #pragma unroll
            for (int nr = 0; nr < 4; ++nr)
                acc[nr] = __builtin_amdgcn_mfma_f32_16x16x32_bf16(
                    a, bf[nr][kc], acc[nr], 0, 0, 0);
        }

        #pragma unroll
        for (int r4 = 0; r4 < 4; ++r4)
            #pragma unroll
            for (int nr = 0; nr < 4; ++nr)
                Cst[(lg * 4 + r4) * 256 + w * 64 + nr * 16 + lr] =
                    f2bf(acc[nr][r4] + bs[nr]);

        asm volatile("s_waitcnt lgkmcnt(0)" ::: "memory");
        __builtin_amdgcn_sched_barrier(0);
        __builtin_amdgcn_s_barrier();     // Cst complete; Alds[buf] free

        const int t3 = t2 + NB;
        const bool has3 = has2 && (t3 < NT);
        if (has3) VP_STAGE(buf, t3);

        {
            const size_t base = (size_t)t * 16 * 256;
            #pragma unroll
            for (int j = 0; j < 2; ++j) {
                const int chunk = j * 256 + tid;
                *(short8*)&C[base + (size_t)chunk * 8] =
                    *(const short8*)&Cst[chunk * 8];
            }
        }

        if (has2) {
            if (has3) { asm volatile("s_waitcnt vmcnt(6)" ::: "memory"); }
            else      { asm volatile("s_waitcnt vmcnt(2)" ::: "memory"); }
        }
        __builtin_amdgcn_sched_barrier(0);
        __builtin_amdgcn_s_barrier();

        if (!has2) break;
        buf ^= 1;
        t = t2; t2 = t3; has2 = has3;
    }
    #undef VP_STAGE
}

// ---------------------------------------------------------------------------
// Fused self-attention (unchanged).
// ---------------------------------------------------------------------------
__global__ __launch_bounds__(256) void attn_fused(
    const float* __restrict__ qh, const float* __restrict__ kh,
    const float* __restrict__ vh, float* __restrict__ sa)
{
    __shared__ short Klds[304 * 40];
    __shared__ short Vtlds[32 * 328];
    const int bh = blockIdx.x, b = bh / NH_, h = bh % NH_;
    const int tid = threadIdx.x;

    for (int idx = tid; idx < 304 * 4; idx += 256) {
        const int key = idx >> 2, dc = idx & 3;
        short8 s = {};
        if (key < LQ_) {
            const float* kp = &kh[((size_t)(b * LQ_ + key)) * D_ + h * HD_ + dc * 8];
            float4 a0 = *reinterpret_cast<const float4*>(kp);
            float4 a1 = *reinterpret_cast<const float4*>(kp + 4);
            s[0] = f2bf(a0.x); s[1] = f2bf(a0.y); s[2] = f2bf(a0.z); s[3] = f2bf(a0.w);
            s[4] = f2bf(a1.x); s[5] = f2bf(a1.y); s[6] = f2bf(a1.z); s[7] = f2bf(a1.w);
        }
        *reinterpret_cast<short8*>(&Klds[key * 40 + dc * 8]) = s;
    }
    for (int idx = tid; idx < LQ_ * 8; idx += 256) {
        const int key = idx >> 3, dc = idx & 7;
        const float4 v4 = *reinterpret_cast<const float4*>(
            &vh[((size_t)(b * LQ_ + key)) * D_ + h * HD_ + dc * 4]);
        Vtlds[(dc * 4 + 0) * 328 + key] = f2bf(v4.x);
        Vtlds[(dc * 4 + 1) * 328 + key] = f2bf(v4.y);
        Vtlds[(dc * 4 + 2) * 328 + key] = f2bf(v4.z);
        Vtlds[(dc * 4 + 3) * 328 + key] = f2bf(v4.w);
    }
    for (int idx = tid; idx < 32 * 20; idx += 256) {
        const int d = idx / 20, kk = idx % 20;
        Vtlds[d * 328 + 300 + kk] = 0;
    }
    __syncthreads();

    const int lane = tid & 63;
    const int wid  = tid >> 6;
    const int g    = lane >> 4;
    const int qc   = lane & 15;
    const int y    = blockIdx.y;
    const int qt_end = (y == 0) ? 10 : 19;

    for (int qt = y * 10 + wid; qt < qt_end; qt += 4) {
        const int q0 = qt * 16;
        short8 qf;
        {
            const int q = min(q0 + qc, LQ_ - 1);
            const float* qp = &qh[((size_t)(b * LQ_ + q)) * D_ + h * HD_ + g * 8];
            float4 a0 = *reinterpret_cast<const float4*>(qp);
            float4 a1 = *reinterpret_cast<const float4*>(qp + 4);
            const float sc = 0.17677669529663687f;
            qf[0] = f2bf(a0.x * sc); qf[1] = f2bf(a0.y * sc);
            qf[2] = f2bf(a0.z * sc); qf[3] = f2bf(a0.w * sc);
            qf[4] = f2bf(a1.x * sc); qf[5] = f2bf(a1.y * sc);
            qf[6] = f2bf(a1.z * sc); qf[7] = f2bf(a1.w * sc);
        }
        f32x4 s[19];
        #pragma unroll
        for (int kt = 0; kt < 19; ++kt) {
            short8 kf = *reinterpret_cast<const short8*>(&Klds[(kt * 16 + qc) * 40 + g * 8]);
            f32x4 z = {};
            s[kt] = __builtin_amdgcn_mfma_f32_16x16x32_bf16(kf, qf, z, 0, 0, 0);
        }
        if (g == 3) { s[18][0] = -1e30f; s[18][1] = -1e30f; s[18][2] = -1e30f; s[18][3] = -1e30f; }

        float m = -1e30f;
        #pragma unroll
        for (int kt = 0; kt < 19; ++kt)
            #pragma unroll
            for (int r = 0; r < 4; ++r) m = fmaxf(m, s[kt][r]);
        m = fmaxf(m, __shfl_xor(m, 16));
        m = fmaxf(m, __shfl_xor(m, 32));
        float sum = 0.f;
        #pragma unroll
        for (int kt = 0; kt < 19; ++kt)
            #pragma unroll
            for (int r = 0; r < 4; ++r) {
                float e = __expf(s[kt][r] - m);
                s[kt][r] = e; sum += e;
            }
        sum += __shfl_xor(sum, 16);
        sum += __shfl_xor(sum, 32);
        const float inv = 1.f / sum;

        unsigned pb0[20], pb1[20];
        #pragma unroll
        for (int kt = 0; kt < 19; ++kt) {
            pb0[kt] = pack_bf2(s[kt][0] * inv, s[kt][1] * inv);
            pb1[kt] = pack_bf2(s[kt][2] * inv, s[kt][3] * inv);
        }
        pb0[19] = 0; pb1[19] = 0;

        f32x4 acc0 = {}, acc1 = {};
        const int src0 = ((g & 1) << 5) + qc;
        const int src1 = src0 + 16;
        const bool hi = (g >> 1);
        #pragma unroll
        for (int c = 0; c < 10; ++c) {
            short8 va0 = *reinterpret_cast<const short8*>(&Vtlds[qc * 328 + c * 32 + g * 8]);
            short8 va1 = *reinterpret_cast<const short8*>(&Vtlds[(qc + 16) * 328 + c * 32 + g * 8]);
            int x0a = __shfl((int)pb0[2 * c], src0), x0b = __shfl((int)pb0[2 * c + 1], src0);
            int x1a = __shfl((int)pb1[2 * c], src0), x1b = __shfl((int)pb1[2 * c + 1], src0);
            int x2a = __shfl((int)pb0[2 * c], src1), x2b = __shfl((int)pb0[2 * c + 1], src1);
            int x3a = __shfl((int)pb1[2 * c], src1), x3b = __shfl((int)pb1[2 * c + 1], src1);
            union { int u[4]; short8 s8; } pb;
            pb.u[0] = hi ? x0b : x0a;
            pb.u[1] = hi ? x1b : x1a;
            pb.u[2] = hi ? x2b : x2a;
            pb.u[3] = hi ? x3b : x3a;
            acc0 = __builtin_amdgcn_mfma_f32_16x16x32_bf16(va0, pb.s8, acc0, 0, 0, 0);
            acc1 = __builtin_amdgcn_mfma_f32_16x16x32_bf16(va1, pb.s8, acc1, 0, 0, 0);
        }

        if (q0 + qc < LQ_) {
            float* op = &sa[((size_t)(b * LQ_ + q0 + qc)) * D_ + h * HD_ + 4 * g];
            *reinterpret_cast<float4*>(op)      = make_float4(acc0[0], acc0[1], acc0[2], acc0[3]);
            *reinterpret_cast<float4*>(op + 16) = make_float4(acc1[0], acc1[1], acc1[2], acc1[3]);
        }
    }
}

// ---------------------------------------------------------------------------
// deformable gather, 16B loads (unchanged).
// ---------------------------------------------------------------------------
__global__ __launch_bounds__(256) void deform_kernel(
    const __hip_bfloat16* __restrict__ val, const float* __restrict__ off,
    const float* __restrict__ aw, const float* __restrict__ rp,
    float* __restrict__ ca)
{
    const int i = blockIdx.x * 256 + threadIdx.x;
    if (i >= NROWS * NH_ * 4) return;
    const int dq = i & 3;
    const int h  = (i >> 2) & 7;
    const int bq = i >> 5;
    const int b  = bq / LQ_;

    const int Hs[4] = {100, 50, 25, 13};
    const int st[4] = {0, 10000, 12500, 13125};

    const float* rpp  = rp  + (size_t)bq * 16;
    const float* offp = off + (size_t)bq * 256 + h * 32;
    const float* awp  = aw  + (size_t)bq * 256 + h * 16;
    const short* vb   = (const short*)val + ((size_t)b * LENV_) * D_ + h * HD_ + dq * 8;

    float wv[16], wmax = -1e30f, wsum = 0.f;
    #pragma unroll
    for (int j = 0; j < 16; ++j) { wv[j] = awp[j]; wmax = fmaxf(wmax, wv[j]); }
    #pragma unroll
    for (int j = 0; j < 16; ++j) { wv[j] = __expf(wv[j] - wmax); wsum += wv[j]; }
    const float winv = 1.f / wsum;

    float acc[8] = {};
    #pragma unroll
    for (int l = 0; l < 4; ++l) {
        const float cx = rpp[l * 4 + 0], cy = rpp[l * 4 + 1];
        const float sw = rpp[l * 4 + 2], sh = rpp[l * 4 + 3];
        const int H = Hs[l], W = Hs[l];
        const int base = st[l];
        #pragma unroll
        for (int p = 0; p < 4; ++p) {
            const float ox = offp[l * 8 + p * 2 + 0];
            const float oy = offp[l * 8 + p * 2 + 1];
            const float x = (cx + ox * 0.125f * sw) * W - 0.5f;
            const float y = (cy + oy * 0.125f * sh) * H - 0.5f;
            const float x0f = floorf(x), y0f = floorf(y);
            const float dx = x - x0f, dy = y - y0f;
            const int x0 = (int)x0f, y0 = (int)y0f;
            const float a = wv[l * 4 + p] * winv;

            float tp[8] = {};
            #pragma unroll
            for (int t = 0; t < 4; ++t) {
                const int ix = x0 + (t & 1);
                const int iy = y0 + (t >> 1);
                const float wx = (t & 1) ? dx : (1.f - dx);
                const float wy = (t >> 1) ? dy : (1.f - dy);
                const bool valid = (ix >= 0) & (ix < W) & (iy >= 0) & (iy < H);
                const int cxi = min(max(ix, 0), W - 1);
                const int cyi = min(max(iy, 0), H - 1);
                const float w = valid ? wx * wy : 0.f;
                const short8 u = *reinterpret_cast<const short8*>(
                    &vb[(size_t)(base + cyi * W + cxi) * D_]);
                #pragma unroll
                for (int k = 0; k < 8; ++k)
                    tp[k] = fmaf(w, bf2f(u[k]), tp[k]);
            }
            #pragma unroll
            for (int k = 0; k < 8; ++k)
                acc[k] = fmaf(a, tp[k], acc[k]);
        }
    }
    float* op = &ca[(size_t)i * 8];
    *reinterpret_cast<float4*>(op)     = make_float4(acc[0], acc[1], acc[2], acc[3]);
    *reinterpret_cast<float4*>(op + 4) = make_float4(acc[4], acc[5], acc[6], acc[7]);
}

// ---------------------------------------------------------------------------
extern "C" void kernel_launch(void* const* d_in, const int* in_sizes, int n_in,
                              void* d_out, int out_size, void* d_ws, size_t ws_size,
                              hipStream_t stream)
{
    const float* tgt    = (const float*)d_in[0];
    const float* refpts = (const float*)d_in[1];
    const float* memory = (const float*)d_in[2];
    const float* Wq  = (const float*)d_in[3];
    const float* Wk  = (const float*)d_in[4];
    const float* Wv  = (const float*)d_in[5];
    const float* Wo  = (const float*)d_in[6];
    const float* Wvp = (const float*)d_in[7];
    const float* Wso = (const float*)d_in[8];
    const float* Waw = (const float*)d_in[9];
    const float* Wop = (const float*)d_in[10];
    const float* W1  = (const float*)d_in[11];
    const float* W2  = (const float*)d_in[12];
    const float* bq  = (const float*)d_in[13];
    const float* bk  = (const float*)d_in[14];
    const float* bv  = (const float*)d_in[15];
    const float* bo  = (const float*)d_in[16];
    const float* bvp = (const float*)d_in[17];
    const float* bso = (const float*)d_in[18];
    const float* baw = (const float*)d_in[19];
    const float* bop = (const float*)d_in[20];
    const float* bf1 = (const float*)d_in[21];
    const float* bf2 = (const float*)d_in[22];
    const float* ln1g = (const float*)d_in[23];
    const float* ln1b = (const float*)d_in[24];
    const float* ln2g = (const float*)d_in[25];
    const float* ln2b = (const float*)d_in[26];
    const float* ln3g = (const float*)d_in[27];
    const float* ln3b = (const float*)d_in[28];
    float* out = (float*)d_out;

    // ---- workspace layout ----
    const size_t SZ = (size_t)NROWS * D_;         // 1,228,800 f32
    float* ws = (float*)d_ws;
    float* reg1 = ws;                             // qh / ca_heads
    float* reg2 = ws + SZ;                        // kh / off_raw
    float* reg3 = ws + 2 * SZ;                    // vh / aw_raw
    float* t    = ws + 3 * SZ;                    // LN1 out
    float* t2   = ws + 4 * SZ;                    // sa_heads -> LN2 out
    float* big  = ws + 5 * SZ;                    // val bf16 -> ff1

    float* qh = reg1;
    float* kh = reg2;
    float* vh = reg3;
    float* sa_heads = t2;
    __hip_bfloat16* val = (__hip_bfloat16*)big;
    float* off_raw = reg2;
    float* aw_raw  = reg3;
    float* ca_heads = reg1;
    float* ff1 = big;

    // weights after the big region
    char* wtbase = (char*)d_ws + 5 * SZ * sizeof(float) + (size_t)VROWS * D_ * 2;
    short* Wqkvt  = (short*)wtbase;               // [768][256]
    short* Wot    = Wqkvt  + 196608;
    short* Wvpt   = Wot    + 65536;
    short* Wsoawt = Wvpt   + 65536;               // [512][256] (rows 384+ zero)
    short* Wopt   = Wsoawt + 131072;
    short* W1t    = Wopt   + 65536;               // [1024][256]
    short* W2t    = W1t    + 262144;              // [256][1024]
    float* bqkv   = (float*)(W2t + 262144);       // [768]
    float* bsoaw  = bqkv + 768;                   // [512]

    const dim3 blk(256);

    // 0) weight prep
    prep_all<<<dim3(4101), blk, 0, stream>>>(
        Wq, Wk, Wv, Wo, Wvp, Wso, Waw, Wop, W1, W2,
        bq, bk, bv, bso, baw,
        Wqkvt, Wot, Wvpt, Wsoawt, Wopt, W1t, W2t, bqkv, bsoaw);

    // 1) fused QKV projection (stacked -> reg1|reg2|reg3), BM=32
    mfma_gemm<0,0,1,0,32><<<dim3(150, 3), blk, 0, stream>>>(
        tgt, Wqkvt, bqkv, reg1, NROWS, 256, D_, nullptr, nullptr, nullptr);

    // 2) fused attention -> sa_heads (t2)
    attn_fused<<<dim3(BS_ * NH_, 2), blk, 0, stream>>>(qh, kh, vh, sa_heads);

    // 3) output proj + fused LN1 -> t
    mfma_gemm<0,0,0,1,32><<<dim3(150, 1), blk, 0, stream>>>(
        sa_heads, Wot, bo, t, NROWS, 256, D_, tgt, ln1g, ln1b);

    // 4) value projection of memory — counted-vmcnt streamer, 4 blocks/CU
    vp_gemm<<<dim3(1024), blk, 0, stream>>>(memory, Wvpt, bvp, (short*)val);

    // 5) fused sampling-offsets + attention-weights (stacked)
    mfma_gemm<0,0,1,0,32><<<dim3(150, 2), blk, 0, stream>>>(
        t, Wsoawt, bsoaw, reg2, NROWS, 256, D_, nullptr, nullptr, nullptr);

    // 6) deformable gather (inline aw softmax, 16B loads)
    deform_kernel<<<dim3((NROWS * NH_ * 4 + 255) / 256), blk, 0, stream>>>(
        val, off_raw, aw_raw, refpts, ca_heads);

    // 7) output proj + fused LN2 -> t2
    mfma_gemm<0,0,0,1,32><<<dim3(150, 1), blk, 0, stream>>>(
        ca_heads, Wopt, bop, t2, NROWS, 256, D_, t, ln2g, ln2b);

    // 8) FFN: W1+relu -> ff1 ; W2 + fused LN3 -> out
    mfma_gemm<1,0,0,0,32><<<dim3(150, 4), blk, 0, stream>>>(
        t2, W1t, bf1, ff1, NROWS, DFF_, D_, nullptr, nullptr, nullptr);
    mfma_gemm<0,0,0,1,32><<<dim3(150, 1), blk, 0, stream>>>(
        ff1, W2t, bf2, out, NROWS, 256, DFF_, t2, ln3g, ln3b);
}

// Round 15
// 205.985 us; speedup vs baseline: 1.7167x; 1.7167x over previous
//
#include <hip/hip_runtime.h>
#include <hip/hip_bf16.h>
#include <cstddef>

#define D_    256
#define NH_   8
#define HD_   32
#define LQ_   300
#define BS_   16
#define LENV_ 13294
#define DFF_  1024
#define NROWS (BS_*LQ_)          // 4800
#define VROWS (BS_*LENV_)        // 212704  (= 32 * 6647 exactly)

typedef __attribute__((ext_vector_type(8))) short short8;
typedef __attribute__((ext_vector_type(4))) float f32x4;
typedef unsigned int u32;

__device__ __forceinline__ short f2bf(float x) {
    unsigned u = __float_as_uint(x);
    u += 0x7fff + ((u >> 16) & 1);     // RNE (inputs are finite)
    return (short)(u >> 16);
}
__device__ __forceinline__ unsigned pack_bf2(float lo, float hi) {
    return (unsigned)(unsigned short)f2bf(lo) | ((unsigned)(unsigned short)f2bf(hi) << 16);
}
__device__ __forceinline__ float bf2f(short s) {
    return __uint_as_float((unsigned)(unsigned short)s << 16);
}

// ---------------------------------------------------------------------------
// Weight prep with LDS-tiled 64x64 transposes (coalesced read AND write).
// Block map: 0..111   7 square 256x256 mats, 16 tiles each
//            112..175 W1 [256][1024] -> [1024][256], 64 tiles
//            176..239 W2 [1024][256] -> [256][1024], 64 tiles
//            240..247 Waw [256][128] -> Wsoawt rows 256..383, 8 tiles
//            248      zero-pad Wsoawt rows 384..511
//            249      fused biases
// ---------------------------------------------------------------------------
__device__ __forceinline__ void tr_tile64(
    const float* __restrict__ src, short* __restrict__ dst,
    int Nsrc, int Kd, int k0, int n0, float (*lds)[65], int tid)
{
    const int tx = tid & 63, ty = tid >> 6;
    #pragma unroll
    for (int j = 0; j < 16; ++j) {
        const int r = ty + j * 4;
        lds[r][tx] = src[(size_t)(k0 + r) * Nsrc + n0 + tx];
    }
    __syncthreads();
    #pragma unroll
    for (int j = 0; j < 16; ++j) {
        const int r = ty + j * 4;           // n-index within tile
        dst[(size_t)(n0 + r) * Kd + k0 + tx] = f2bf(lds[tx][r]);
    }
}

__global__ __launch_bounds__(256) void prep_all(
    const float* __restrict__ Wq, const float* __restrict__ Wk,
    const float* __restrict__ Wv, const float* __restrict__ Wo,
    const float* __restrict__ Wvp, const float* __restrict__ Wso,
    const float* __restrict__ Waw, const float* __restrict__ Wop,
    const float* __restrict__ W1, const float* __restrict__ W2,
    const float* __restrict__ bqp, const float* __restrict__ bkp,
    const float* __restrict__ bvp, const float* __restrict__ bsop,
    const float* __restrict__ bawp,
    short* __restrict__ Wqkvt, short* __restrict__ Wot,
    short* __restrict__ Wvpt, short* __restrict__ Wsoawt,
    short* __restrict__ Wopt, short* __restrict__ W1t,
    short* __restrict__ W2t, float* __restrict__ bqkv,
    float* __restrict__ bsoaw)
{
    __shared__ float lds[64][65];
    const int blk = blockIdx.x, tid = threadIdx.x;

    if (blk < 112) {                       // 7 square transposes
        const int seg = blk >> 4, tile = blk & 15;
        const int k0 = (tile >> 2) * 64, n0 = (tile & 3) * 64;
        const float* src; short* dst;
        switch (seg) {
            case 0: src = Wq;  dst = Wqkvt;          break;
            case 1: src = Wk;  dst = Wqkvt + 65536;  break;
            case 2: src = Wv;  dst = Wqkvt + 131072; break;
            case 3: src = Wo;  dst = Wot;            break;
            case 4: src = Wvp; dst = Wvpt;           break;
            case 5: src = Wso; dst = Wsoawt;         break;
            default: src = Wop; dst = Wopt;          break;
        }
        tr_tile64(src, dst, 256, 256, k0, n0, lds, tid);
    } else if (blk < 176) {                // W1 [256][1024] -> [1024][256]
        const int tile = blk - 112;
        const int k0 = (tile >> 4) * 64, n0 = (tile & 15) * 64;
        tr_tile64(W1, W1t, 1024, 256, k0, n0, lds, tid);
    } else if (blk < 240) {                // W2 [1024][256] -> [256][1024]
        const int tile = blk - 176;
        const int k0 = (tile >> 2) * 64, n0 = (tile & 3) * 64;
        tr_tile64(W2, W2t, 256, 1024, k0, n0, lds, tid);
    } else if (blk < 248) {                // Waw [256][128] -> rows 256..383
        const int tile = blk - 240;
        const int k0 = (tile >> 1) * 64, n0 = (tile & 1) * 64;
        tr_tile64(Waw, Wsoawt + 65536, 128, 256, k0, n0, lds, tid);
    } else if (blk == 248) {               // zero-pad rows 384..511
        for (int i = tid; i < 32768; i += 256) Wsoawt[98304 + i] = 0;
    } else {                               // biases
        for (int e = tid; e < 1280; e += 256) {
            if (e < 768)
                bqkv[e] = (e < 256) ? bqp[e] : (e < 512) ? bkp[e - 256] : bvp[e - 512];
            else {
                const int f = e - 768;
                bsoaw[f] = (f < 256) ? bsop[f] : (f < 384) ? bawp[f - 256] : 0.f;
            }
        }
    }
}

// ---------------------------------------------------------------------------
// Pipelined bf16 MFMA GEMM, tile BM x 256 (BM = 64 or 32).
// FUSE_LN=1 (requires N=256, STACKED=0, M%BM==0): out = LN(acc+bias+resid)*g+b
// ---------------------------------------------------------------------------
template<int ACT, int OUT_BF16, int STACKED, int FUSE_LN, int BM>
__global__ __launch_bounds__(256) void mfma_gemm(
    const float* __restrict__ A, const short* __restrict__ Wt,
    const float* __restrict__ bias, void* __restrict__ Cout,
    int M, int N, int K,
    const float* __restrict__ resid, const float* __restrict__ lng,
    const float* __restrict__ lnb)
{
    constexpr int MR = BM / 16;
    __shared__ short Alds[2][BM * 40];
    __shared__ short Blds[2][256 * 40];
    const int tid  = threadIdx.x;
    const int lane = tid & 63;
    const int wn   = tid >> 6;
    const int m0   = blockIdx.x * BM;
    const int nb   = blockIdx.y;
    const int srow = tid >> 2;              // 0..63
    const int schk = tid & 3;

    const bool sA   = (BM == 64) || (srow < BM);
    const int  arow = m0 + (sA ? srow : 0);
    const bool aok  = sA && (arow < M);
    const float* aptr = &A[(size_t)(aok ? arow : 0) * K + schk * 8];
    const short* bptr = &Wt[(size_t)(nb * 256 + srow) * K + schk * 8];

    f32x4 acc[MR][4] = {};
    float4 ra0, ra1;
    short8 rb0, rb1, rb2, rb3;

    ra0 = make_float4(0.f, 0.f, 0.f, 0.f); ra1 = ra0;
    if (aok) { ra0 = *(const float4*)(aptr); ra1 = *(const float4*)(aptr + 4); }
    rb0 = *(const short8*)(bptr);
    rb1 = *(const short8*)(bptr + (size_t)64 * K);
    rb2 = *(const short8*)(bptr + (size_t)128 * K);
    rb3 = *(const short8*)(bptr + (size_t)192 * K);
    {
        if (sA) {
            short8 s;
            s[0] = f2bf(ra0.x); s[1] = f2bf(ra0.y); s[2] = f2bf(ra0.z); s[3] = f2bf(ra0.w);
            s[4] = f2bf(ra1.x); s[5] = f2bf(ra1.y); s[6] = f2bf(ra1.z); s[7] = f2bf(ra1.w);
            *(short8*)&Alds[0][srow * 40 + schk * 8] = s;
        }
        *(short8*)&Blds[0][(srow +   0) * 40 + schk * 8] = rb0;
        *(short8*)&Blds[0][(srow +  64) * 40 + schk * 8] = rb1;
        *(short8*)&Blds[0][(srow + 128) * 40 + schk * 8] = rb2;
        *(short8*)&Blds[0][(srow + 192) * 40 + schk * 8] = rb3;
    }
    __syncthreads();

    const int lg = lane >> 4;
    const int lr = lane & 15;
    int buf = 0;

    for (int k0 = 32; k0 < K; k0 += 32) {
        ra0 = make_float4(0.f, 0.f, 0.f, 0.f); ra1 = ra0;
        if (aok) { ra0 = *(const float4*)(aptr + k0); ra1 = *(const float4*)(aptr + k0 + 4); }
        rb0 = *(const short8*)(bptr + k0);
        rb1 = *(const short8*)(bptr + k0 + (size_t)64 * K);
        rb2 = *(const short8*)(bptr + k0 + (size_t)128 * K);
        rb3 = *(const short8*)(bptr + k0 + (size_t)192 * K);

        {
            short8 a[MR], b[4];
            #pragma unroll
            for (int mr = 0; mr < MR; ++mr)
                a[mr] = *(const short8*)&Alds[buf][(mr * 16 + lr) * 40 + lg * 8];
            #pragma unroll
            for (int nr = 0; nr < 4; ++nr)
                b[nr] = *(const short8*)&Blds[buf][(wn * 64 + nr * 16 + lr) * 40 + lg * 8];
            #pragma unroll
            for (int mr = 0; mr < MR; ++mr)
                #pragma unroll
                for (int nr = 0; nr < 4; ++nr)
                    acc[mr][nr] = __builtin_amdgcn_mfma_f32_16x16x32_bf16(
                        a[mr], b[nr], acc[mr][nr], 0, 0, 0);
        }

        {
            const int ob = buf ^ 1;
            if (sA) {
                short8 s;
                s[0] = f2bf(ra0.x); s[1] = f2bf(ra0.y); s[2] = f2bf(ra0.z); s[3] = f2bf(ra0.w);
                s[4] = f2bf(ra1.x); s[5] = f2bf(ra1.y); s[6] = f2bf(ra1.z); s[7] = f2bf(ra1.w);
                *(short8*)&Alds[ob][srow * 40 + schk * 8] = s;
            }
            *(short8*)&Blds[ob][(srow +   0) * 40 + schk * 8] = rb0;
            *(short8*)&Blds[ob][(srow +  64) * 40 + schk * 8] = rb1;
            *(short8*)&Blds[ob][(srow + 128) * 40 + schk * 8] = rb2;
            *(short8*)&Blds[ob][(srow + 192) * 40 + schk * 8] = rb3;
        }
        __syncthreads();
        buf ^= 1;
    }

    {
        short8 a[MR], b[4];
        #pragma unroll
        for (int mr = 0; mr < MR; ++mr)
            a[mr] = *(const short8*)&Alds[buf][(mr * 16 + lr) * 40 + lg * 8];
        #pragma unroll
        for (int nr = 0; nr < 4; ++nr)
            b[nr] = *(const short8*)&Blds[buf][(wn * 64 + nr * 16 + lr) * 40 + lg * 8];
        #pragma unroll
        for (int mr = 0; mr < MR; ++mr)
            #pragma unroll
            for (int nr = 0; nr < 4; ++nr)
                acc[mr][nr] = __builtin_amdgcn_mfma_f32_16x16x32_bf16(
                    a[mr], b[nr], acc[mr][nr], 0, 0, 0);
    }

    if (FUSE_LN) {
        __shared__ float RedS[4][BM];
        __shared__ float RedS2[4][BM];
        float psum[MR][4] = {};
        float psq[MR][4]  = {};
        #pragma unroll
        for (int mr = 0; mr < MR; ++mr)
            #pragma unroll
            for (int r4 = 0; r4 < 4; ++r4) {
                const int row = m0 + mr * 16 + lg * 4 + r4;
                #pragma unroll
                for (int nr = 0; nr < 4; ++nr) {
                    const int col = wn * 64 + nr * 16 + lr;
                    float x = acc[mr][nr][r4] + bias[col]
                            + resid[(size_t)row * 256 + col];
                    acc[mr][nr][r4] = x;
                    psum[mr][r4] += x;
                    psq[mr][r4]  += x * x;
                }
            }
        #pragma unroll
        for (int o = 1; o < 16; o <<= 1)
            #pragma unroll
            for (int mr = 0; mr < MR; ++mr)
                #pragma unroll
                for (int r4 = 0; r4 < 4; ++r4) {
                    psum[mr][r4] += __shfl_xor(psum[mr][r4], o);
                    psq[mr][r4]  += __shfl_xor(psq[mr][r4], o);
                }
        if (lr == 0) {
            #pragma unroll
            for (int mr = 0; mr < MR; ++mr)
                #pragma unroll
                for (int r4 = 0; r4 < 4; ++r4) {
                    const int lrow = mr * 16 + lg * 4 + r4;
                    RedS[wn][lrow]  = psum[mr][r4];
                    RedS2[wn][lrow] = psq[mr][r4];
                }
        }
        __syncthreads();
        float* outp = (float*)Cout;
        #pragma unroll
        for (int mr = 0; mr < MR; ++mr)
            #pragma unroll
            for (int r4 = 0; r4 < 4; ++r4) {
                const int lrow = mr * 16 + lg * 4 + r4;
                const int row  = m0 + lrow;
                const float s  = RedS[0][lrow] + RedS[1][lrow] + RedS[2][lrow] + RedS[3][lrow];
                const float s2 = RedS2[0][lrow] + RedS2[1][lrow] + RedS2[2][lrow] + RedS2[3][lrow];
                const float mean = s * (1.f / 256.f);
                const float var  = s2 * (1.f / 256.f) - mean * mean;
                const float inv  = rsqrtf(var + 1e-5f);
                #pragma unroll
                for (int nr = 0; nr < 4; ++nr) {
                    const int col = wn * 64 + nr * 16 + lr;
                    outp[(size_t)row * 256 + col] =
                        (acc[mr][nr][r4] - mean) * inv * lng[col] + lnb[col];
                }
            }
        return;
    }

    if (STACKED) {
        float* Cb = (float*)Cout + (size_t)nb * M * 256;
        const float* bb = bias + nb * 256;
        #pragma unroll
        for (int mr = 0; mr < MR; ++mr)
            #pragma unroll
            for (int r = 0; r < 4; ++r) {
                const int row = m0 + mr * 16 + lg * 4 + r;
                if (row >= M) continue;
                #pragma unroll
                for (int nr = 0; nr < 4; ++nr) {
                    const int col = wn * 64 + nr * 16 + lr;
                    Cb[(size_t)row * 256 + col] = acc[mr][nr][r] + bb[col];
                }
            }
    } else {
        #pragma unroll
        for (int mr = 0; mr < MR; ++mr)
            #pragma unroll
            for (int r = 0; r < 4; ++r) {
                const int row = m0 + mr * 16 + lg * 4 + r;
                if (row >= M) continue;
                #pragma unroll
                for (int nr = 0; nr < 4; ++nr) {
                    const int col = nb * 256 + wn * 64 + nr * 16 + lr;
                    float v = acc[mr][nr][r] + bias[col];
                    if (ACT) v = fmaxf(v, 0.f);
                    if (OUT_BF16) ((short*)Cout)[(size_t)row * N + col] = f2bf(v);
                    else          ((float*)Cout)[(size_t)row * N + col] = v;
                }
            }
    }
}

// ---------------------------------------------------------------------------
// Value-projection (K=N=256) — R13's proven counted-vmcnt async streamer:
// 32-row tiles, 512 blocks (2 blocks/CU), never drains vmcnt to 0 mid-loop.
// ---------------------------------------------------------------------------
__global__ __launch_bounds__(256, 2) void vp_gemm(
    const float* __restrict__ A, const short* __restrict__ Wt,
    const float* __restrict__ bias, short* __restrict__ C)
{
    __shared__ float Alds[2][32 * 256];   // 2 x 32 KB
    __shared__ short Cst[32 * 256];       // 16 KB
    const int tid  = threadIdx.x;
    const int lane = tid & 63;
    const int w    = tid >> 6;
    const int lr   = lane & 15;
    const int lg   = lane >> 4;

    short8 bf[4][8];
    #pragma unroll
    for (int nr = 0; nr < 4; ++nr) {
        const short* wp = &Wt[(size_t)(w * 64 + nr * 16 + lr) * 256 + lg * 8];
        #pragma unroll
        for (int kc = 0; kc < 8; ++kc)
            bf[nr][kc] = *(const short8*)(wp + kc * 32);
    }
    float bs[4];
    #pragma unroll
    for (int nr = 0; nr < 4; ++nr) bs[nr] = bias[w * 64 + nr * 16 + lr];

    const int NT = VROWS / 32;            // 6647 exact
    const int NB = 512;

    #define VP_STAGE(BUFI, TILE)                                               \
        {                                                                      \
            _Pragma("unroll")                                                  \
            for (int j = 0; j < 8; ++j) {                                      \
                const int r = w * 8 + j;                                       \
                const int grow = (TILE) * 32 + r;                              \
                const int c16 = ((((lane >> 1) ^ (r & 7)) << 1) | (lane & 1)); \
                const float* src = A + (size_t)grow * 256 + c16 * 4;           \
                __builtin_amdgcn_global_load_lds(                              \
                    (const __attribute__((address_space(1))) u32*)src,         \
                    (__attribute__((address_space(3))) u32*)&Alds[BUFI][r*256],\
                    16, 0, 0);                                                 \
            }                                                                  \
        }

    int t  = blockIdx.x;
    int t2 = t + NB;
    bool has2 = (t2 < NT);
    int buf = 0;

    VP_STAGE(0, t);
    if (has2) VP_STAGE(1, t2);
    if (has2) { asm volatile("s_waitcnt vmcnt(8)" ::: "memory"); }
    else      { asm volatile("s_waitcnt vmcnt(0)" ::: "memory"); }
    __builtin_amdgcn_sched_barrier(0);
    __builtin_amdgcn_s_barrier();

    while (true) {
        f32x4 acc[2][4] = {};
        #pragma unroll
        for (int kc = 0; kc < 8; ++kc) {
            short8 a[2];
            #pragma unroll
            for (int mr = 0; mr < 2; ++mr) {
                const int row = mr * 16 + lr;
                const int c32 = (kc * 4 + lg) ^ (row & 7);
                const float* p = &Alds[buf][row * 256 + c32 * 8];
                float4 x = *(const float4*)(p);
                float4 y = *(const float4*)(p + 4);
                short8 s;
                s[0] = f2bf(x.x); s[1] = f2bf(x.y); s[2] = f2bf(x.z); s[3] = f2bf(x.w);
                s[4] = f2bf(y.x); s[5] = f2bf(y.y); s[6] = f2bf(y.z); s[7] = f2bf(y.w);
                a[mr] = s;
            }
            #pragma unroll
            for (int mr = 0; mr < 2; ++mr)
                #pragma unroll
                for (int nr = 0; nr < 4; ++nr)
                    acc[mr][nr] = __builtin_amdgcn_mfma_f32_16x16x32_bf16(
                        a[mr], bf[nr][kc], acc[mr][nr], 0, 0, 0);
        }

        #pragma unroll
        for (int mr = 0; mr < 2; ++mr)
            #pragma unroll
            for (int r4 = 0; r4 < 4; ++r4)
                #pragma unroll
                for (int nr = 0; nr < 4; ++nr)
                    Cst[(mr * 16 + lg * 4 + r4) * 256 + w * 64 + nr * 16 + lr] =
                        f2bf(acc[mr][nr][r4] + bs[nr]);

        asm volatile("s_waitcnt lgkmcnt(0)" ::: "memory");
        __builtin_amdgcn_sched_barrier(0);
        __builtin_amdgcn_s_barrier();     // Cst complete; Alds[buf] free

        const int t3 = t2 + NB;
        const bool has3 = has2 && (t3 < NT);
        if (has3) VP_STAGE(buf, t3);

        {
            const size_t base = (size_t)t * 32 * 256;
            #pragma unroll
            for (int j = 0; j < 4; ++j) {
                const int chunk = j * 256 + tid;
                *(short8*)&C[base + (size_t)chunk * 8] =
                    *(const short8*)&Cst[chunk * 8];
            }
        }

        if (has2) {
            if (has3) { asm volatile("s_waitcnt vmcnt(12)" ::: "memory"); }
            else      { asm volatile("s_waitcnt vmcnt(4)"  ::: "memory"); }
        }
        __builtin_amdgcn_sched_barrier(0);
        __builtin_amdgcn_s_barrier();

        if (!has2) break;
        buf ^= 1;
        t = t2; t2 = t3; has2 = has3;
    }
    #undef VP_STAGE
}

// ---------------------------------------------------------------------------
// Fused self-attention (unchanged).
// ---------------------------------------------------------------------------
__global__ __launch_bounds__(256) void attn_fused(
    const float* __restrict__ qh, const float* __restrict__ kh,
    const float* __restrict__ vh, float* __restrict__ sa)
{
    __shared__ short Klds[304 * 40];
    __shared__ short Vtlds[32 * 328];
    const int bh = blockIdx.x, b = bh / NH_, h = bh % NH_;
    const int tid = threadIdx.x;

    for (int idx = tid; idx < 304 * 4; idx += 256) {
        const int key = idx >> 2, dc = idx & 3;
        short8 s = {};
        if (key < LQ_) {
            const float* kp = &kh[((size_t)(b * LQ_ + key)) * D_ + h * HD_ + dc * 8];
            float4 a0 = *reinterpret_cast<const float4*>(kp);
            float4 a1 = *reinterpret_cast<const float4*>(kp + 4);
            s[0] = f2bf(a0.x); s[1] = f2bf(a0.y); s[2] = f2bf(a0.z); s[3] = f2bf(a0.w);
            s[4] = f2bf(a1.x); s[5] = f2bf(a1.y); s[6] = f2bf(a1.z); s[7] = f2bf(a1.w);
        }
        *reinterpret_cast<short8*>(&Klds[key * 40 + dc * 8]) = s;
    }
    for (int idx = tid; idx < LQ_ * 8; idx += 256) {
        const int key = idx >> 3, dc = idx & 7;
        const float4 v4 = *reinterpret_cast<const float4*>(
            &vh[((size_t)(b * LQ_ + key)) * D_ + h * HD_ + dc * 4]);
        Vtlds[(dc * 4 + 0) * 328 + key] = f2bf(v4.x);
        Vtlds[(dc * 4 + 1) * 328 + key] = f2bf(v4.y);
        Vtlds[(dc * 4 + 2) * 328 + key] = f2bf(v4.z);
        Vtlds[(dc * 4 + 3) * 328 + key] = f2bf(v4.w);
    }
    for (int idx = tid; idx < 32 * 20; idx += 256) {
        const int d = idx / 20, kk = idx % 20;
        Vtlds[d * 328 + 300 + kk] = 0;
    }
    __syncthreads();

    const int lane = tid & 63;
    const int wid  = tid >> 6;
    const int g    = lane >> 4;
    const int qc   = lane & 15;
    const int y    = blockIdx.y;
    const int qt_end = (y == 0) ? 10 : 19;

    for (int qt = y * 10 + wid; qt < qt_end; qt += 4) {
        const int q0 = qt * 16;
        short8 qf;
        {
            const int q = min(q0 + qc, LQ_ - 1);
            const float* qp = &qh[((size_t)(b * LQ_ + q)) * D_ + h * HD_ + g * 8];
            float4 a0 = *reinterpret_cast<const float4*>(qp);
            float4 a1 = *reinterpret_cast<const float4*>(qp + 4);
            const float sc = 0.17677669529663687f;
            qf[0] = f2bf(a0.x * sc); qf[1] = f2bf(a0.y * sc);
            qf[2] = f2bf(a0.z * sc); qf[3] = f2bf(a0.w * sc);
            qf[4] = f2bf(a1.x * sc); qf[5] = f2bf(a1.y * sc);
            qf[6] = f2bf(a1.z * sc); qf[7] = f2bf(a1.w * sc);
        }
        f32x4 s[19];
        #pragma unroll
        for (int kt = 0; kt < 19; ++kt) {
            short8 kf = *reinterpret_cast<const short8*>(&Klds[(kt * 16 + qc) * 40 + g * 8]);
            f32x4 z = {};
            s[kt] = __builtin_amdgcn_mfma_f32_16x16x32_bf16(kf, qf, z, 0, 0, 0);
        }
        if (g == 3) { s[18][0] = -1e30f; s[18][1] = -1e30f; s[18][2] = -1e30f; s[18][3] = -1e30f; }

        float m = -1e30f;
        #pragma unroll
        for (int kt = 0; kt < 19; ++kt)
            #pragma unroll
            for (int r = 0; r < 4; ++r) m = fmaxf(m, s[kt][r]);
        m = fmaxf(m, __shfl_xor(m, 16));
        m = fmaxf(m, __shfl_xor(m, 32));
        float sum = 0.f;
        #pragma unroll
        for (int kt = 0; kt < 19; ++kt)
            #pragma unroll
            for (int r = 0; r < 4; ++r) {
                float e = __expf(s[kt][r] - m);
                s[kt][r] = e; sum += e;
            }
        sum += __shfl_xor(sum, 16);
        sum += __shfl_xor(sum, 32);
        const float inv = 1.f / sum;

        unsigned pb0[20], pb1[20];
        #pragma unroll
        for (int kt = 0; kt < 19; ++kt) {
            pb0[kt] = pack_bf2(s[kt][0] * inv, s[kt][1] * inv);
            pb1[kt] = pack_bf2(s[kt][2] * inv, s[kt][3] * inv);
        }
        pb0[19] = 0; pb1[19] = 0;

        f32x4 acc0 = {}, acc1 = {};
        const int src0 = ((g & 1) << 5) + qc;
        const int src1 = src0 + 16;
        const bool hi = (g >> 1);
        #pragma unroll
        for (int c = 0; c < 10; ++c) {
            short8 va0 = *reinterpret_cast<const short8*>(&Vtlds[qc * 328 + c * 32 + g * 8]);
            short8 va1 = *reinterpret_cast<const short8*>(&Vtlds[(qc + 16) * 328 + c * 32 + g * 8]);
            int x0a = __shfl((int)pb0[2 * c], src0), x0b = __shfl((int)pb0[2 * c + 1], src0);
            int x1a = __shfl((int)pb1[2 * c], src0), x1b = __shfl((int)pb1[2 * c + 1], src0);
            int x2a = __shfl((int)pb0[2 * c], src1), x2b = __shfl((int)pb0[2 * c + 1], src1);
            int x3a = __shfl((int)pb1[2 * c], src1), x3b = __shfl((int)pb1[2 * c + 1], src1);
            union { int u[4]; short8 s8; } pb;
            pb.u[0] = hi ? x0b : x0a;
            pb.u[1] = hi ? x1b : x1a;
            pb.u[2] = hi ? x2b : x2a;
            pb.u[3] = hi ? x3b : x3a;
            acc0 = __builtin_amdgcn_mfma_f32_16x16x32_bf16(va0, pb.s8, acc0, 0, 0, 0);
            acc1 = __builtin_amdgcn_mfma_f32_16x16x32_bf16(va1, pb.s8, acc1, 0, 0, 0);
        }

        if (q0 + qc < LQ_) {
            float* op = &sa[((size_t)(b * LQ_ + q0 + qc)) * D_ + h * HD_ + 4 * g];
            *reinterpret_cast<float4*>(op)      = make_float4(acc0[0], acc0[1], acc0[2], acc0[3]);
            *reinterpret_cast<float4*>(op + 16) = make_float4(acc1[0], acc1[1], acc1[2], acc1[3]);
        }
    }
}

// ---------------------------------------------------------------------------
// deformable gather, 16B loads (unchanged).
// ---------------------------------------------------------------------------
__global__ __launch_bounds__(256) void deform_kernel(
    const __hip_bfloat16* __restrict__ val, const float* __restrict__ off,
    const float* __restrict__ aw, const float* __restrict__ rp,
    float* __restrict__ ca)
{
    const int i = blockIdx.x * 256 + threadIdx.x;
    if (i >= NROWS * NH_ * 4) return;
    const int dq = i & 3;
    const int h  = (i >> 2) & 7;
    const int bq = i >> 5;
    const int b  = bq / LQ_;

    const int Hs[4] = {100, 50, 25, 13};
    const int st[4] = {0, 10000, 12500, 13125};

    const float* rpp  = rp  + (size_t)bq * 16;
    const float* offp = off + (size_t)bq * 256 + h * 32;
    const float* awp  = aw  + (size_t)bq * 256 + h * 16;
    const short* vb   = (const short*)val + ((size_t)b * LENV_) * D_ + h * HD_ + dq * 8;

    float wv[16], wmax = -1e30f, wsum = 0.f;
    #pragma unroll
    for (int j = 0; j < 16; ++j) { wv[j] = awp[j]; wmax = fmaxf(wmax, wv[j]); }
    #pragma unroll
    for (int j = 0; j < 16; ++j) { wv[j] = __expf(wv[j] - wmax); wsum += wv[j]; }
    const float winv = 1.f / wsum;

    float acc[8] = {};
    #pragma unroll
    for (int l = 0; l < 4; ++l) {
        const float cx = rpp[l * 4 + 0], cy = rpp[l * 4 + 1];
        const float sw = rpp[l * 4 + 2], sh = rpp[l * 4 + 3];
        const int H = Hs[l], W = Hs[l];
        const int base = st[l];
        #pragma unroll
        for (int p = 0; p < 4; ++p) {
            const float ox = offp[l * 8 + p * 2 + 0];
            const float oy = offp[l * 8 + p * 2 + 1];
            const float x = (cx + ox * 0.125f * sw) * W - 0.5f;
            const float y = (cy + oy * 0.125f * sh) * H - 0.5f;
            const float x0f = floorf(x), y0f = floorf(y);
            const float dx = x - x0f, dy = y - y0f;
            const int x0 = (int)x0f, y0 = (int)y0f;
            const float a = wv[l * 4 + p] * winv;

            float tp[8] = {};
            #pragma unroll
            for (int t = 0; t < 4; ++t) {
                const int ix = x0 + (t & 1);
                const int iy = y0 + (t >> 1);
                const float wx = (t & 1) ? dx : (1.f - dx);
                const float wy = (t >> 1) ? dy : (1.f - dy);
                const bool valid = (ix >= 0) & (ix < W) & (iy >= 0) & (iy < H);
                const int cxi = min(max(ix, 0), W - 1);
                const int cyi = min(max(iy, 0), H - 1);
                const float w = valid ? wx * wy : 0.f;
                const short8 u = *reinterpret_cast<const short8*>(
                    &vb[(size_t)(base + cyi * W + cxi) * D_]);
                #pragma unroll
                for (int k = 0; k < 8; ++k)
                    tp[k] = fmaf(w, bf2f(u[k]), tp[k]);
            }
            #pragma unroll
            for (int k = 0; k < 8; ++k)
                acc[k] = fmaf(a, tp[k], acc[k]);
        }
    }
    float* op = &ca[(size_t)i * 8];
    *reinterpret_cast<float4*>(op)     = make_float4(acc[0], acc[1], acc[2], acc[3]);
    *reinterpret_cast<float4*>(op + 4) = make_float4(acc[4], acc[5], acc[6], acc[7]);
}

// ---------------------------------------------------------------------------
extern "C" void kernel_launch(void* const* d_in, const int* in_sizes, int n_in,
                              void* d_out, int out_size, void* d_ws, size_t ws_size,
                              hipStream_t stream)
{
    const float* tgt    = (const float*)d_in[0];
    const float* refpts = (const float*)d_in[1];
    const float* memory = (const float*)d_in[2];
    const float* Wq  = (const float*)d_in[3];
    const float* Wk  = (const float*)d_in[4];
    const float* Wv  = (const float*)d_in[5];
    const float* Wo  = (const float*)d_in[6];
    const float* Wvp = (const float*)d_in[7];
    const float* Wso = (const float*)d_in[8];
    const float* Waw = (const float*)d_in[9];
    const float* Wop = (const float*)d_in[10];
    const float* W1  = (const float*)d_in[11];
    const float* W2  = (const float*)d_in[12];
    const float* bq  = (const float*)d_in[13];
    const float* bk  = (const float*)d_in[14];
    const float* bv  = (const float*)d_in[15];
    const float* bo  = (const float*)d_in[16];
    const float* bvp = (const float*)d_in[17];
    const float* bso = (const float*)d_in[18];
    const float* baw = (const float*)d_in[19];
    const float* bop = (const float*)d_in[20];
    const float* bf1 = (const float*)d_in[21];
    const float* bf2 = (const float*)d_in[22];
    const float* ln1g = (const float*)d_in[23];
    const float* ln1b = (const float*)d_in[24];
    const float* ln2g = (const float*)d_in[25];
    const float* ln2b = (const float*)d_in[26];
    const float* ln3g = (const float*)d_in[27];
    const float* ln3b = (const float*)d_in[28];
    float* out = (float*)d_out;

    // ---- workspace layout ----
    const size_t SZ = (size_t)NROWS * D_;         // 1,228,800 f32
    float* ws = (float*)d_ws;
    float* reg1 = ws;                             // qh / ca_heads
    float* reg2 = ws + SZ;                        // kh / off_raw
    float* reg3 = ws + 2 * SZ;                    // vh / aw_raw
    float* t    = ws + 3 * SZ;                    // LN1 out
    float* t2   = ws + 4 * SZ;                    // sa_heads -> LN2 out
    float* big  = ws + 5 * SZ;                    // val bf16 -> ff1

    float* qh = reg1;
    float* kh = reg2;
    float* vh = reg3;
    float* sa_heads = t2;
    __hip_bfloat16* val = (__hip_bfloat16*)big;
    float* off_raw = reg2;
    float* aw_raw  = reg3;
    float* ca_heads = reg1;
    float* ff1 = big;

    // weights after the big region
    char* wtbase = (char*)d_ws + 5 * SZ * sizeof(float) + (size_t)VROWS * D_ * 2;
    short* Wqkvt  = (short*)wtbase;               // [768][256]
    short* Wot    = Wqkvt  + 196608;
    short* Wvpt   = Wot    + 65536;
    short* Wsoawt = Wvpt   + 65536;               // [512][256] (rows 384+ zero)
    short* Wopt   = Wsoawt + 131072;
    short* W1t    = Wopt   + 65536;               // [1024][256]
    short* W2t    = W1t    + 262144;              // [256][1024]
    float* bqkv   = (float*)(W2t + 262144);       // [768]
    float* bsoaw  = bqkv + 768;                   // [512]

    const dim3 blk(256);

    // 0) weight prep (LDS-tiled coalesced transposes)
    prep_all<<<dim3(250), blk, 0, stream>>>(
        Wq, Wk, Wv, Wo, Wvp, Wso, Waw, Wop, W1, W2,
        bq, bk, bv, bso, baw,
        Wqkvt, Wot, Wvpt, Wsoawt, Wopt, W1t, W2t, bqkv, bsoaw);

    // 1) fused QKV projection (stacked -> reg1|reg2|reg3), BM=32
    mfma_gemm<0,0,1,0,32><<<dim3(150, 3), blk, 0, stream>>>(
        tgt, Wqkvt, bqkv, reg1, NROWS, 256, D_, nullptr, nullptr, nullptr);

    // 2) fused attention -> sa_heads (t2)
    attn_fused<<<dim3(BS_ * NH_, 2), blk, 0, stream>>>(qh, kh, vh, sa_heads);

    // 3) output proj + fused LN1 -> t
    mfma_gemm<0,0,0,1,32><<<dim3(150, 1), blk, 0, stream>>>(
        sa_heads, Wot, bo, t, NROWS, 256, D_, tgt, ln1g, ln1b);

    // 4) value projection of memory — R13 counted-vmcnt streamer
    vp_gemm<<<dim3(512), blk, 0, stream>>>(memory, Wvpt, bvp, (short*)val);

    // 5) fused sampling-offsets + attention-weights (stacked)
    mfma_gemm<0,0,1,0,32><<<dim3(150, 2), blk, 0, stream>>>(
        t, Wsoawt, bsoaw, reg2, NROWS, 256, D_, nullptr, nullptr, nullptr);

    // 6) deformable gather (inline aw softmax, 16B loads)
    deform_kernel<<<dim3((NROWS * NH_ * 4 + 255) / 256), blk, 0, stream>>>(
        val, off_raw, aw_raw, refpts, ca_heads);

    // 7) output proj + fused LN2 -> t2
    mfma_gemm<0,0,0,1,32><<<dim3(150, 1), blk, 0, stream>>>(
        ca_heads, Wopt, bop, t2, NROWS, 256, D_, t, ln2g, ln2b);

    // 8) FFN: W1+relu -> ff1 ; W2 + fused LN3 -> out
    mfma_gemm<1,0,0,0,32><<<dim3(150, 4), blk, 0, stream>>>(
        t2, W1t, bf1, ff1, NROWS, DFF_, D_, nullptr, nullptr, nullptr);
    mfma_gemm<0,0,0,1,32><<<dim3(150, 1), blk, 0, stream>>>(
        ff1, W2t, bf2, out, NROWS, 256, DFF_, t2, ln3g, ln3b);
}